// Round 4
// baseline (256.254 us; speedup 1.0000x reference)
//
#include <hip/hip_runtime.h>
#include <hip/hip_bf16.h>

#define B_    256
#define NKV   128
#define NQ    512
#define CDIM  192
#define QCDIM 96
#define NH    6
#define DH    32
#define SCALE 0.17677669529663687f
#define LOG2E 1.4426950408889634f

typedef __hip_bfloat16 bf16;
typedef __attribute__((ext_vector_type(8))) short s16x8;
typedef __attribute__((ext_vector_type(4))) float f32x4;
#define MFMA16(a, b, c) __builtin_amdgcn_mfma_f32_16x16x32_bf16(a, b, c, 0, 0, 0)

// ---- workspace layout (bytes). *F tensors are MFMA-fragment-ordered:
// [...frag...][lane(64)][elems] so a wave reads one fragment as one coalesced
// 16 B/lane global_load_dwordx4. biasF is in S-output (C-layout) order.
// wqF/biasF are pre-scaled by LOG2E so softmax exp is a bare v_exp_f32. ----
#define OFF_BIASF 0                        // fp32 [6][32][8][64][4]     = 1,572,864
#define OFF_WKVF  1572864                  // bf16 [24][6][64][8]        = 147,456
#define OFF_WQF   1720320                  // bf16 [6][2][3][64][8]      = 36,864 (×SCALE×LOG2E)
#define OFF_WPF   1757184                  // bf16 [6][6][64][8]         = 36,864
#define OFF_KF    1794048                  // bf16 [B_][6][8][64][8]     = 12,582,912
#define OFF_VF    14376960                 // bf16 [B_][6][2][4][64][8]  = 12,582,912
// total 26,959,872 B

// One kernel for all precomputation: biasF (98304 thr) + wkvF/wqF/wpF (110592 thr)
__global__ __launch_bounds__(256)
void precomp_all(const float* __restrict__ w_kv, const float* __restrict__ w_q,
                 const float* __restrict__ w_proj, const float* __restrict__ bias_table,
                 const int* __restrict__ rel_index,
                 float* __restrict__ biasF, bf16* __restrict__ wkvF,
                 bf16* __restrict__ wqF, bf16* __restrict__ wpF)
{
    const int i = blockIdx.x * 256 + threadIdx.x;   // 208896 total
    if (i < 98304) {                                // biasF[h][rowblk][tl][lane][r]
        const int lane = i & 63, tl = (i >> 6) & 7, rowblk = (i >> 9) & 31, h = i >> 14;
        const int quad = lane >> 4, l16 = lane & 15;
        const int kvi = tl * 16 + l16;
        float vr[4];
        #pragma unroll
        for (int r = 0; r < 4; ++r) {
            const int qrow = rowblk * 16 + quad * 4 + r;
            vr[r] = bias_table[rel_index[qrow * NKV + kvi] * NH + h] * LOG2E;
        }
        *(float4*)&biasF[i * 4] = make_float4(vr[0], vr[1], vr[2], vr[3]);
    } else if (i < 98304 + 73728) {                 // wkvF[nt24][kk6][lane][j]
        const int i1 = i - 98304;
        const int j = i1 & 7, lane = (i1 >> 3) & 63, kk = (i1 >> 9) % 6, nt = i1 / 3072;
        const int quad = lane >> 4, l16 = lane & 15;
        wkvF[i1] = __float2bfloat16(w_kv[(kk * 32 + quad * 8 + j) * (2 * CDIM) + nt * 16 + l16]);
    } else if (i < 98304 + 92160) {                 // wqF[h][tl2][kk3][lane][j]
        const int i2 = i - 98304 - 73728;
        const int j = i2 & 7, lane = (i2 >> 3) & 63, kk = (i2 >> 9) % 3,
                  tl = (i2 / 1536) & 1, h = i2 / 3072;
        const int quad = lane >> 4, l16 = lane & 15;
        wqF[i2] = __float2bfloat16(w_q[(kk * 32 + quad * 8 + j) * CDIM + h * DH + tl * 16 + l16]
                                   * (SCALE * LOG2E));
    } else {                                        // wpF[h][tn6][lane][j]
        const int i3 = i - 98304 - 92160;
        const int j = i3 & 7, lane = (i3 >> 3) & 63, tn = (i3 >> 9) % 6, h = i3 / 3072;
        const int quad = lane >> 4, l16 = lane & 15;
        wpF[i3] = __float2bfloat16(w_proj[(h * DH + quad * 8 + j) * QCDIM + tn * 16 + l16]);
    }
}

// Per (batch, half): half 0 -> K' -> KF frag order; half 1 -> V' -> VF frag order.
__global__ __launch_bounds__(512, 4)
void proj_kv(const float* __restrict__ kv, const float* __restrict__ b_kv,
             const bf16* __restrict__ wkvF, bf16* __restrict__ KF, bf16* __restrict__ VF)
{
    __shared__ __align__(16) char smem[52224];
    bf16* sA = (bf16*)smem;                        // staging [128][200]
    const int b = blockIdx.x, half = blockIdx.y, t = threadIdx.x;
    const int w = t >> 6, lane = t & 63, quad = lane >> 4, l16 = lane & 15;
    const f32x4 ZV = {0.f, 0.f, 0.f, 0.f};

    for (int f = t; f < 6144; f += 512) {
        const int r = f / 48, c4 = f % 48;
        const float4 v = *(const float4*)&kv[((size_t)b * NKV + r) * CDIM + c4 * 4];
        __align__(8) bf16 tmp[4] = {__float2bfloat16(v.x), __float2bfloat16(v.y),
                                    __float2bfloat16(v.z), __float2bfloat16(v.w)};
        *(uint2*)&sA[r * 200 + c4 * 4] = *(uint2*)tmp;
    }
    __syncthreads();

    f32x4 acc[12];
    #pragma unroll
    for (int i = 0; i < 12; ++i) acc[i] = ZV;
    for (int kk = 0; kk < 6; ++kk) {
        const s16x8 a = *(const s16x8*)&sA[(w * 16 + l16) * 200 + kk * 32 + quad * 8];
        #pragma unroll
        for (int nt = 0; nt < 12; ++nt) {
            const s16x8 bb = *(const s16x8*)&wkvF[(((half * 12 + nt) * 6 + kk) * 64 + lane) * 8];
            acc[nt] = MFMA16(a, bb, acc[nt]);
        }
    }
    __syncthreads();   // staging dead; reuse smem as transpose buffer

    if (half == 0) {
        bf16* bufK = (bf16*)smem;                  // K' [128][200]
        #pragma unroll
        for (int nt = 0; nt < 12; ++nt) {
            const int col = nt * 16 + l16;
            const float bias = b_kv[col];
            #pragma unroll
            for (int r = 0; r < 4; ++r)
                bufK[(w * 16 + quad * 4 + r) * 200 + col] = __float2bfloat16(acc[nt][r] + bias);
        }
        __syncthreads();
        bf16* KF_b = KF + (size_t)b * 24576;       // [h][tl8][lane][8]
        #pragma unroll
        for (int i = 0; i < 6; ++i) {
            const int fr = w * 6 + i, h = fr >> 3, tl = fr & 7;
            const s16x8 v = *(const s16x8*)&bufK[(tl * 16 + l16) * 200 + h * DH + quad * 8];
            *(s16x8*)&KF_b[(size_t)(fr * 64 + lane) * 8] = v;
        }
    } else {
        bf16* bufV = (bf16*)smem;                  // V'^T [192][136]
        #pragma unroll
        for (int nt = 0; nt < 12; ++nt) {
            const int d = nt * 16 + l16;
            const float bias = b_kv[CDIM + d];
            __align__(8) bf16 tmp[4];
            #pragma unroll
            for (int r = 0; r < 4; ++r) tmp[r] = __float2bfloat16(acc[nt][r] + bias);
            *(uint2*)&bufV[d * 136 + w * 16 + quad * 4] = *(uint2*)tmp;
        }
        __syncthreads();
        bf16* VF_b = VF + (size_t)b * 24576;       // [h][tl2][kk4][lane][8]
        #pragma unroll
        for (int i = 0; i < 6; ++i) {
            const int fr = w * 6 + i, h = fr >> 3, tl = (fr >> 2) & 1, kk = fr & 3;
            const s16x8 v = *(const s16x8*)&bufV[(h * DH + tl * 16 + l16) * 136 + kk * 32 + quad * 8];
            *(s16x8*)&VF_b[(size_t)(fr * 64 + lane) * 8] = v;
        }
    }
}

// Per (batch, 64-row pair-chunk): 4 waves; each wave owns TWO independent
// 16-row chains, PHASE-INTERLEAVED: every phase issues both chains' ops so
// chain 1 covers chain 0's LDS-roundtrip/MFMA latency. B-side fragments
// (wqF/KF/VF/wpF) are chain-invariant -> loaded once, used by both MFMAs.
// launch_bounds(256,3): ~170-reg unified budget -> no spills (spills at
// (256,6)/(256,8) doubled WRITE_SIZE and erased all gains). No barriers:
// patches wave-private (in-order DS).
__global__ __launch_bounds__(256, 3)
void attn_fused(const float* __restrict__ q, const float* __restrict__ b_q,
                const float* __restrict__ b_proj, const char* __restrict__ wsro,
                float* __restrict__ out)
{
    __shared__ __align__(16) bf16 sP[8 * 16 * 136];   // 34,816 B
    const int b = blockIdx.x, y = blockIdx.y;         // y in 0..3
    const int t = threadIdx.x;
    const int w = t >> 6, lane = t & 63, quad = lane >> 4, l16 = lane & 15;

    const float* biasF = (const float*)(wsro + OFF_BIASF);
    const bf16*  wqF   = (const bf16*)(wsro + OFF_WQF);
    const bf16*  wpF   = (const bf16*)(wsro + OFF_WPF);
    const bf16*  KF_b  = (const bf16*)(wsro + OFF_KF) + (size_t)b * 24576;
    const bf16*  VF_b  = (const bf16*)(wsro + OFF_VF) + (size_t)b * 24576;

    const int rb[2] = { y * 8 + w, y * 8 + w + 4 };   // two row-blocks per wave
    bf16* myP[2] = { sP + (2 * w) * 2176, sP + (2 * w + 1) * 2176 };

    // q A-fragments for both chains, fp32 -> bf16 in-kernel
    s16x8 qa[2][3];
    #pragma unroll
    for (int c = 0; c < 2; ++c)
        #pragma unroll
        for (int kk = 0; kk < 3; ++kk) {
            const float* src = &q[((size_t)b * NQ + rb[c] * 16 + l16) * QCDIM + kk * 32 + quad * 8];
            const float4 a0 = *(const float4*)src;
            const float4 a1 = *(const float4*)(src + 4);
            __align__(16) bf16 tmp[8] = {
                __float2bfloat16(a0.x), __float2bfloat16(a0.y), __float2bfloat16(a0.z),
                __float2bfloat16(a0.w), __float2bfloat16(a1.x), __float2bfloat16(a1.y),
                __float2bfloat16(a1.z), __float2bfloat16(a1.w)};
            qa[c][kk] = *(s16x8*)tmp;
        }

    // out accumulator initialized with b_proj (folds the epilogue bias add)
    f32x4 outacc[2][6];
    #pragma unroll
    for (int c = 0; c < 2; ++c)
        #pragma unroll
        for (int tn = 0; tn < 6; ++tn) {
            const float bp = b_proj[tn * 16 + l16];
            outacc[c][tn] = (f32x4){bp, bp, bp, bp};
        }

    for (int h = 0; h < NH; ++h) {
        // ---- (a) Q'_h = q @ wq_h (pre-scaled by SCALE*LOG2E), both chains ----
        f32x4 qacc[2][2];
        #pragma unroll
        for (int tl = 0; tl < 2; ++tl) {
            const float bq = b_q[h * DH + tl * 16 + l16] * (SCALE * LOG2E);
            qacc[0][tl] = (f32x4){bq, bq, bq, bq};
            qacc[1][tl] = (f32x4){bq, bq, bq, bq};
        }
        #pragma unroll
        for (int kk = 0; kk < 3; ++kk)
            #pragma unroll
            for (int tl = 0; tl < 2; ++tl) {
                const s16x8 bb = *(const s16x8*)&wqF[(((h * 2 + tl) * 3 + kk) * 64 + lane) * 8];
                qacc[0][tl] = MFMA16(qa[0][kk], bb, qacc[0][tl]);
                qacc[1][tl] = MFMA16(qa[1][kk], bb, qacc[1][tl]);
            }
        #pragma unroll
        for (int c = 0; c < 2; ++c)
            #pragma unroll
            for (int tl = 0; tl < 2; ++tl)
                #pragma unroll
                for (int r = 0; r < 4; ++r)
                    myP[c][(quad * 4 + r) * 136 + tl * 16 + l16] = __float2bfloat16(qacc[c][tl][r]);
        s16x8 aQ[2];
        aQ[0] = *(const s16x8*)&myP[0][l16 * 136 + quad * 8];
        aQ[1] = *(const s16x8*)&myP[1][l16 * 136 + quad * 8];

        // ---- (b) S = Q'K'^T + bias (C-init; pre-scaled by LOG2E); 2^S; P;
        //          row-sums. KF fragments shared across chains. ----
        float rs[2][4] = {{0.f, 0.f, 0.f, 0.f}, {0.f, 0.f, 0.f, 0.f}};
        #pragma unroll
        for (int half = 0; half < 2; ++half) {
            f32x4 sacc[2][4];
            #pragma unroll
            for (int c = 0; c < 2; ++c)
                #pragma unroll
                for (int t4 = 0; t4 < 4; ++t4)
                    sacc[c][t4] = *(const f32x4*)&biasF[(((h * 32 + rb[c]) * 8 + half * 4 + t4) * 64 + lane) * 4];
            #pragma unroll
            for (int t4 = 0; t4 < 4; ++t4) {
                const s16x8 bb = *(const s16x8*)&KF_b[(size_t)((h * 8 + half * 4 + t4) * 64 + lane) * 8];
                sacc[0][t4] = MFMA16(aQ[0], bb, sacc[0][t4]);
                sacc[1][t4] = MFMA16(aQ[1], bb, sacc[1][t4]);
            }
            #pragma unroll
            for (int c = 0; c < 2; ++c)
                #pragma unroll
                for (int t4 = 0; t4 < 4; ++t4)
                    #pragma unroll
                    for (int r = 0; r < 4; ++r) {
                        const float vv = __builtin_amdgcn_exp2f(sacc[c][t4][r]);
                        rs[c][r] += vv;
                        myP[c][(quad * 4 + r) * 136 + (half * 4 + t4) * 16 + l16] = __float2bfloat16(vv);
                    }
        }
        float inv[2][4];
        #pragma unroll
        for (int c = 0; c < 2; ++c)
            #pragma unroll
            for (int r = 0; r < 4; ++r) {
                float s = rs[c][r];
                #pragma unroll
                for (int off = 1; off < 16; off <<= 1) s += __shfl_xor(s, off, 16);
                inv[c][r] = 1.f / s;
            }

        // ---- (c) O_h = P_unnorm @ V'_h; V fragments shared across chains ----
        f32x4 oacc[2][2];
        oacc[0][0] = (f32x4){0.f, 0.f, 0.f, 0.f}; oacc[0][1] = (f32x4){0.f, 0.f, 0.f, 0.f};
        oacc[1][0] = (f32x4){0.f, 0.f, 0.f, 0.f}; oacc[1][1] = (f32x4){0.f, 0.f, 0.f, 0.f};
        #pragma unroll
        for (int kk = 0; kk < 4; ++kk) {
            s16x8 aP[2];
            aP[0] = *(const s16x8*)&myP[0][l16 * 136 + kk * 32 + quad * 8];
            aP[1] = *(const s16x8*)&myP[1][l16 * 136 + kk * 32 + quad * 8];
            #pragma unroll
            for (int tl = 0; tl < 2; ++tl) {
                const s16x8 bb = *(const s16x8*)&VF_b[(size_t)(((h * 2 + tl) * 4 + kk) * 64 + lane) * 8];
                oacc[0][tl] = MFMA16(aP[0], bb, oacc[0][tl]);
                oacc[1][tl] = MFMA16(aP[1], bb, oacc[1][tl]);
            }
        }
        #pragma unroll
        for (int c = 0; c < 2; ++c)
            #pragma unroll
            for (int tl = 0; tl < 2; ++tl)
                #pragma unroll
                for (int r = 0; r < 4; ++r)
                    myP[c][(quad * 4 + r) * 136 + tl * 16 + l16] = __float2bfloat16(oacc[c][tl][r] * inv[c][r]);
        s16x8 aO[2];
        aO[0] = *(const s16x8*)&myP[0][l16 * 136 + quad * 8];
        aO[1] = *(const s16x8*)&myP[1][l16 * 136 + quad * 8];

        // ---- (d) out += O_h @ wp_h; wp fragments shared across chains ----
        #pragma unroll
        for (int tn = 0; tn < 6; ++tn) {
            const s16x8 bb = *(const s16x8*)&wpF[((h * 6 + tn) * 64 + lane) * 8];
            outacc[0][tn] = MFMA16(aO[0], bb, outacc[0][tn]);
            outacc[1][tn] = MFMA16(aO[1], bb, outacc[1][tn]);
        }
    }

    #pragma unroll
    for (int c = 0; c < 2; ++c)
        #pragma unroll
        for (int tn = 0; tn < 6; ++tn)
            #pragma unroll
            for (int r = 0; r < 4; ++r)
                out[((size_t)b * NQ + rb[c] * 16 + quad * 4 + r) * QCDIM + tn * 16 + l16]
                    = outacc[c][tn][r];
}

extern "C" void kernel_launch(void* const* d_in, const int* in_sizes, int n_in,
                              void* d_out, int out_size, void* d_ws, size_t ws_size,
                              hipStream_t stream)
{
    const float* kv       = (const float*)d_in[0];
    const float* q        = (const float*)d_in[1];
    const float* w_kv     = (const float*)d_in[2];
    const float* b_kv     = (const float*)d_in[3];
    const float* w_q      = (const float*)d_in[4];
    const float* b_q      = (const float*)d_in[5];
    const float* w_proj   = (const float*)d_in[6];
    const float* b_proj   = (const float*)d_in[7];
    const float* bias_tab = (const float*)d_in[8];
    const int*   rel_idx  = (const int*)d_in[9];
    char* ws = (char*)d_ws;

    precomp_all<<<816, 256, 0, stream>>>(w_kv, w_q, w_proj, bias_tab, rel_idx,
                                         (float*)(ws + OFF_BIASF), (bf16*)(ws + OFF_WKVF),
                                         (bf16*)(ws + OFF_WQF), (bf16*)(ws + OFF_WPF));
    proj_kv<<<dim3(B_, 2), 512, 0, stream>>>(kv, b_kv, (const bf16*)(ws + OFF_WKVF),
                                             (bf16*)(ws + OFF_KF), (bf16*)(ws + OFF_VF));
    attn_fused<<<dim3(B_, 4), 256, 0, stream>>>(q, b_q, b_proj, (const char*)ws,
                                                (float*)d_out);
}

// Round 5
// 242.414 us; speedup vs baseline: 1.0571x; 1.0571x over previous
//
#include <hip/hip_runtime.h>
#include <hip/hip_bf16.h>

#define B_    256
#define NKV   128
#define NQ    512
#define CDIM  192
#define QCDIM 96
#define NH    6
#define DH    32
#define SCALE 0.17677669529663687f
#define LOG2E 1.4426950408889634f

typedef __hip_bfloat16 bf16;
typedef __attribute__((ext_vector_type(8))) short s16x8;
typedef __attribute__((ext_vector_type(4))) float f32x4;
#define MFMA16(a, b, c) __builtin_amdgcn_mfma_f32_16x16x32_bf16(a, b, c, 0, 0, 0)

// ---- workspace layout (bytes). *F tensors are MFMA-fragment-ordered:
// [...frag...][lane(64)][elems] so a wave reads one fragment as one coalesced
// 16 B/lane global_load_dwordx4. biasF is in S-output (C-layout) order.
// wqF/biasF are pre-scaled by LOG2E so softmax exp is a bare v_exp_f32. ----
#define OFF_BIASF 0                        // fp32 [6][32][8][64][4]     = 1,572,864
#define OFF_WKVF  1572864                  // bf16 [24][6][64][8]        = 147,456
#define OFF_WQF   1720320                  // bf16 [6][2][3][64][8]      = 36,864 (×SCALE×LOG2E)
#define OFF_WPF   1757184                  // bf16 [6][6][64][8]         = 36,864
#define OFF_KF    1794048                  // bf16 [B_][6][8][64][8]     = 12,582,912
#define OFF_VF    14376960                 // bf16 [B_][6][2][4][64][8]  = 12,582,912
// total 26,959,872 B

// One kernel for all precomputation: biasF (98304 thr) + wkvF/wqF/wpF (110592 thr)
__global__ __launch_bounds__(256)
void precomp_all(const float* __restrict__ w_kv, const float* __restrict__ w_q,
                 const float* __restrict__ w_proj, const float* __restrict__ bias_table,
                 const int* __restrict__ rel_index,
                 float* __restrict__ biasF, bf16* __restrict__ wkvF,
                 bf16* __restrict__ wqF, bf16* __restrict__ wpF)
{
    const int i = blockIdx.x * 256 + threadIdx.x;   // 208896 total
    if (i < 98304) {                                // biasF[h][rowblk][tl][lane][r]
        const int lane = i & 63, tl = (i >> 6) & 7, rowblk = (i >> 9) & 31, h = i >> 14;
        const int quad = lane >> 4, l16 = lane & 15;
        const int kvi = tl * 16 + l16;
        float vr[4];
        #pragma unroll
        for (int r = 0; r < 4; ++r) {
            const int qrow = rowblk * 16 + quad * 4 + r;
            vr[r] = bias_table[rel_index[qrow * NKV + kvi] * NH + h] * LOG2E;
        }
        *(float4*)&biasF[i * 4] = make_float4(vr[0], vr[1], vr[2], vr[3]);
    } else if (i < 98304 + 73728) {                 // wkvF[nt24][kk6][lane][j]
        const int i1 = i - 98304;
        const int j = i1 & 7, lane = (i1 >> 3) & 63, kk = (i1 >> 9) % 6, nt = i1 / 3072;
        const int quad = lane >> 4, l16 = lane & 15;
        wkvF[i1] = __float2bfloat16(w_kv[(kk * 32 + quad * 8 + j) * (2 * CDIM) + nt * 16 + l16]);
    } else if (i < 98304 + 92160) {                 // wqF[h][tl2][kk3][lane][j]
        const int i2 = i - 98304 - 73728;
        const int j = i2 & 7, lane = (i2 >> 3) & 63, kk = (i2 >> 9) % 3,
                  tl = (i2 / 1536) & 1, h = i2 / 3072;
        const int quad = lane >> 4, l16 = lane & 15;
        wqF[i2] = __float2bfloat16(w_q[(kk * 32 + quad * 8 + j) * CDIM + h * DH + tl * 16 + l16]
                                   * (SCALE * LOG2E));
    } else {                                        // wpF[h][tn6][lane][j]
        const int i3 = i - 98304 - 92160;
        const int j = i3 & 7, lane = (i3 >> 3) & 63, tn = (i3 >> 9) % 6, h = i3 / 3072;
        const int quad = lane >> 4, l16 = lane & 15;
        wpF[i3] = __float2bfloat16(w_proj[(h * DH + quad * 8 + j) * QCDIM + tn * 16 + l16]);
    }
}

// Per (batch, half): half 0 -> K' -> KF frag order; half 1 -> V' -> VF frag order.
__global__ __launch_bounds__(512, 4)
void proj_kv(const float* __restrict__ kv, const float* __restrict__ b_kv,
             const bf16* __restrict__ wkvF, bf16* __restrict__ KF, bf16* __restrict__ VF)
{
    __shared__ __align__(16) char smem[52224];
    bf16* sA = (bf16*)smem;                        // staging [128][200]
    const int b = blockIdx.x, half = blockIdx.y, t = threadIdx.x;
    const int w = t >> 6, lane = t & 63, quad = lane >> 4, l16 = lane & 15;
    const f32x4 ZV = {0.f, 0.f, 0.f, 0.f};

    for (int f = t; f < 6144; f += 512) {
        const int r = f / 48, c4 = f % 48;
        const float4 v = *(const float4*)&kv[((size_t)b * NKV + r) * CDIM + c4 * 4];
        __align__(8) bf16 tmp[4] = {__float2bfloat16(v.x), __float2bfloat16(v.y),
                                    __float2bfloat16(v.z), __float2bfloat16(v.w)};
        *(uint2*)&sA[r * 200 + c4 * 4] = *(uint2*)tmp;
    }
    __syncthreads();

    f32x4 acc[12];
    #pragma unroll
    for (int i = 0; i < 12; ++i) acc[i] = ZV;
    for (int kk = 0; kk < 6; ++kk) {
        const s16x8 a = *(const s16x8*)&sA[(w * 16 + l16) * 200 + kk * 32 + quad * 8];
        #pragma unroll
        for (int nt = 0; nt < 12; ++nt) {
            const s16x8 bb = *(const s16x8*)&wkvF[(((half * 12 + nt) * 6 + kk) * 64 + lane) * 8];
            acc[nt] = MFMA16(a, bb, acc[nt]);
        }
    }
    __syncthreads();   // staging dead; reuse smem as transpose buffer

    if (half == 0) {
        bf16* bufK = (bf16*)smem;                  // K' [128][200]
        #pragma unroll
        for (int nt = 0; nt < 12; ++nt) {
            const int col = nt * 16 + l16;
            const float bias = b_kv[col];
            #pragma unroll
            for (int r = 0; r < 4; ++r)
                bufK[(w * 16 + quad * 4 + r) * 200 + col] = __float2bfloat16(acc[nt][r] + bias);
        }
        __syncthreads();
        bf16* KF_b = KF + (size_t)b * 24576;       // [h][tl8][lane][8]
        #pragma unroll
        for (int i = 0; i < 6; ++i) {
            const int fr = w * 6 + i, h = fr >> 3, tl = fr & 7;
            const s16x8 v = *(const s16x8*)&bufK[(tl * 16 + l16) * 200 + h * DH + quad * 8];
            *(s16x8*)&KF_b[(size_t)(fr * 64 + lane) * 8] = v;
        }
    } else {
        bf16* bufV = (bf16*)smem;                  // V'^T [192][136]
        #pragma unroll
        for (int nt = 0; nt < 12; ++nt) {
            const int d = nt * 16 + l16;
            const float bias = b_kv[CDIM + d];
            __align__(8) bf16 tmp[4];
            #pragma unroll
            for (int r = 0; r < 4; ++r) tmp[r] = __float2bfloat16(acc[nt][r] + bias);
            *(uint2*)&bufV[d * 136 + w * 16 + quad * 4] = *(uint2*)tmp;
        }
        __syncthreads();
        bf16* VF_b = VF + (size_t)b * 24576;       // [h][tl2][kk4][lane][8]
        #pragma unroll
        for (int i = 0; i < 6; ++i) {
            const int fr = w * 6 + i, h = fr >> 3, tl = (fr >> 2) & 1, kk = fr & 3;
            const s16x8 v = *(const s16x8*)&bufV[(h * DH + tl * 16 + l16) * 136 + kk * 32 + quad * 8];
            *(s16x8*)&VF_b[(size_t)(fr * 64 + lane) * 8] = v;
        }
    }
}

// HEAD-PARALLEL attention: grid (B, 32 rowblocks), block = 384 thr = 6 waves.
// Wave w owns head w end-to-end (Q-proj -> QK^T+exp -> PV) for ONE 16-row
// block — the 6-head serial loop of previous versions becomes 6 parallel
// waves (per-wave chain ~6x shorter). Head outputs are additive under the
// final projection: each wave deposits its normalized 16x32 O_h into a
// shared LDS O-tile (disjoint columns, no race), one barrier, then the 6
// waves cooperatively do out = O @ w_proj (wave w computes n-tile w).
// launch_bounds(384,6): 85-reg budget, per-wave state ~50 regs -> no spills
// (spilling at tighter bounds doubled WRITE_SIZE in R2/R3 and erased gains).
__global__ __launch_bounds__(384, 6)
void attn_fused(const float* __restrict__ q, const float* __restrict__ b_q,
                const float* __restrict__ b_proj, const char* __restrict__ wsro,
                float* __restrict__ out)
{
    __shared__ __align__(16) bf16 sP[6 * 16 * 136];   // per-wave patches, 26,112 B
    __shared__ __align__(16) bf16 sO[16 * 200];       // shared O-tile,     6,400 B
    const int b = blockIdx.x, rb = blockIdx.y;        // rb in 0..31
    const int t = threadIdx.x;
    const int h = t >> 6, lane = t & 63, quad = lane >> 4, l16 = lane & 15;

    const float* biasF = (const float*)(wsro + OFF_BIASF);
    const bf16*  wqF   = (const bf16*)(wsro + OFF_WQF);
    const bf16*  wpF   = (const bf16*)(wsro + OFF_WPF);
    const bf16*  KF_b  = (const bf16*)(wsro + OFF_KF) + (size_t)b * 24576;
    const bf16*  VF_b  = (const bf16*)(wsro + OFF_VF) + (size_t)b * 24576;

    bf16* myP = sP + h * 2176;

    // ---- (a) Q'_h = q @ wq_h (pre-scaled by SCALE*LOG2E) + b_q splat ----
    f32x4 qacc[2];
    #pragma unroll
    for (int tl = 0; tl < 2; ++tl) {
        const float bq = b_q[h * DH + tl * 16 + l16] * (SCALE * LOG2E);
        qacc[tl] = (f32x4){bq, bq, bq, bq};
    }
    #pragma unroll
    for (int kk = 0; kk < 3; ++kk) {
        const float* src = &q[((size_t)b * NQ + rb * 16 + l16) * QCDIM + kk * 32 + quad * 8];
        const float4 a0 = *(const float4*)src;
        const float4 a1 = *(const float4*)(src + 4);
        __align__(16) bf16 tmp[8] = {
            __float2bfloat16(a0.x), __float2bfloat16(a0.y), __float2bfloat16(a0.z),
            __float2bfloat16(a0.w), __float2bfloat16(a1.x), __float2bfloat16(a1.y),
            __float2bfloat16(a1.z), __float2bfloat16(a1.w)};
        const s16x8 qa = *(s16x8*)tmp;
        #pragma unroll
        for (int tl = 0; tl < 2; ++tl) {
            const s16x8 bb = *(const s16x8*)&wqF[(((h * 2 + tl) * 3 + kk) * 64 + lane) * 8];
            qacc[tl] = MFMA16(qa, bb, qacc[tl]);
        }
    }
    #pragma unroll
    for (int tl = 0; tl < 2; ++tl)
        #pragma unroll
        for (int r = 0; r < 4; ++r)
            myP[(quad * 4 + r) * 136 + tl * 16 + l16] = __float2bfloat16(qacc[tl][r]);
    const s16x8 aQ = *(const s16x8*)&myP[l16 * 136 + quad * 8];

    // ---- (b) S = Q'K'^T + bias (C-init, pre-scaled by LOG2E); 2^S -> P;
    //          row-sums. No max subtraction: |scores| are small. ----
    float rs[4] = {0.f, 0.f, 0.f, 0.f};
    #pragma unroll
    for (int half = 0; half < 2; ++half) {
        f32x4 sacc[4];
        #pragma unroll
        for (int t4 = 0; t4 < 4; ++t4)
            sacc[t4] = *(const f32x4*)&biasF[(((h * 32 + rb) * 8 + half * 4 + t4) * 64 + lane) * 4];
        #pragma unroll
        for (int t4 = 0; t4 < 4; ++t4) {
            const s16x8 bb = *(const s16x8*)&KF_b[(size_t)((h * 8 + half * 4 + t4) * 64 + lane) * 8];
            sacc[t4] = MFMA16(aQ, bb, sacc[t4]);
        }
        #pragma unroll
        for (int t4 = 0; t4 < 4; ++t4)
            #pragma unroll
            for (int r = 0; r < 4; ++r) {
                const float vv = __builtin_amdgcn_exp2f(sacc[t4][r]);
                rs[r] += vv;
                myP[(quad * 4 + r) * 136 + (half * 4 + t4) * 16 + l16] = __float2bfloat16(vv);
            }
    }
    float inv[4];
    #pragma unroll
    for (int r = 0; r < 4; ++r) {
        float s = rs[r];
        #pragma unroll
        for (int off = 1; off < 16; off <<= 1) s += __shfl_xor(s, off, 16);
        inv[r] = 1.f / s;
    }

    // ---- (c) O_h = (P_unnorm @ V'_h) * inv -> shared O-tile cols h*32.. ----
    f32x4 oacc[2];
    oacc[0] = (f32x4){0.f, 0.f, 0.f, 0.f};
    oacc[1] = (f32x4){0.f, 0.f, 0.f, 0.f};
    #pragma unroll
    for (int kk = 0; kk < 4; ++kk) {
        const s16x8 aP = *(const s16x8*)&myP[l16 * 136 + kk * 32 + quad * 8];
        #pragma unroll
        for (int tl = 0; tl < 2; ++tl) {
            const s16x8 bb = *(const s16x8*)&VF_b[(size_t)(((h * 2 + tl) * 4 + kk) * 64 + lane) * 8];
            oacc[tl] = MFMA16(aP, bb, oacc[tl]);
        }
    }
    #pragma unroll
    for (int tl = 0; tl < 2; ++tl)
        #pragma unroll
        for (int r = 0; r < 4; ++r)
            sO[(quad * 4 + r) * 200 + h * DH + tl * 16 + l16] = __float2bfloat16(oacc[tl][r] * inv[r]);

    __syncthreads();   // O-tile complete (all 6 heads' columns)

    // ---- (d) out n-tile h: acc = b_proj splat; sum over 6 k-blocks ----
    f32x4 acc;
    {
        const float bp = b_proj[h * 16 + l16];
        acc = (f32x4){bp, bp, bp, bp};
    }
    #pragma unroll
    for (int kk = 0; kk < 6; ++kk) {
        const s16x8 aO = *(const s16x8*)&sO[l16 * 200 + kk * 32 + quad * 8];
        const s16x8 bb = *(const s16x8*)&wpF[((kk * 6 + h) * 64 + lane) * 8];
        acc = MFMA16(aO, bb, acc);
    }
    #pragma unroll
    for (int r = 0; r < 4; ++r)
        out[((size_t)b * NQ + rb * 16 + quad * 4 + r) * QCDIM + h * 16 + l16] = acc[r];
}

extern "C" void kernel_launch(void* const* d_in, const int* in_sizes, int n_in,
                              void* d_out, int out_size, void* d_ws, size_t ws_size,
                              hipStream_t stream)
{
    const float* kv       = (const float*)d_in[0];
    const float* q        = (const float*)d_in[1];
    const float* w_kv     = (const float*)d_in[2];
    const float* b_kv     = (const float*)d_in[3];
    const float* w_q      = (const float*)d_in[4];
    const float* b_q      = (const float*)d_in[5];
    const float* w_proj   = (const float*)d_in[6];
    const float* b_proj   = (const float*)d_in[7];
    const float* bias_tab = (const float*)d_in[8];
    const int*   rel_idx  = (const int*)d_in[9];
    char* ws = (char*)d_ws;

    precomp_all<<<816, 256, 0, stream>>>(w_kv, w_q, w_proj, bias_tab, rel_idx,
                                         (float*)(ws + OFF_BIASF), (bf16*)(ws + OFF_WKVF),
                                         (bf16*)(ws + OFF_WQF), (bf16*)(ws + OFF_WPF));
    proj_kv<<<dim3(B_, 2), 512, 0, stream>>>(kv, b_kv, (const bf16*)(ws + OFF_WKVF),
                                             (bf16*)(ws + OFF_KF), (bf16*)(ws + OFF_VF));
    attn_fused<<<dim3(B_, 32), 384, 0, stream>>>(q, b_q, b_proj, (const char*)ws,
                                                 (float*)d_out);
}

// Round 6
// 210.838 us; speedup vs baseline: 1.2154x; 1.1498x over previous
//
#include <hip/hip_runtime.h>
#include <hip/hip_bf16.h>

#define B_    256
#define NKV   128
#define NQ    512
#define CDIM  192
#define QCDIM 96
#define NH    6
#define DH    32
#define SCALE 0.17677669529663687f
#define LOG2E 1.4426950408889634f

typedef __hip_bfloat16 bf16;
typedef __attribute__((ext_vector_type(8))) short s16x8;
typedef __attribute__((ext_vector_type(4))) short s16x4;
typedef __attribute__((ext_vector_type(4))) float f32x4;
#define MFMA16(a, b, c) __builtin_amdgcn_mfma_f32_16x16x32_bf16(a, b, c, 0, 0, 0)

__device__ __forceinline__ float b2f(short s) {
    return __uint_as_float(((unsigned)(unsigned short)s) << 16);
}

// ---- workspace layout (bytes). *F tensors are MFMA-fragment-ordered:
// [...frag...][lane(64)][elems] so a wave reads one fragment as one coalesced
// global_load. biasF is bf16 (halves the 393 MB logical bias stream and its
// register footprint for prefetch). wqF/biasF pre-scaled by LOG2E. ----
#define OFF_BIASF 0                        // bf16 [6][32][8][64][4]     = 786,432
#define OFF_WKVF  786432                   // bf16 [24][6][64][8]        = 147,456
#define OFF_WQF   933888                   // bf16 [6][2][3][64][8]      = 36,864 (×SCALE×LOG2E)
#define OFF_WPF   970752                   // bf16 [6][6][64][8]         = 36,864
#define OFF_KF    1007616                  // bf16 [B_][6][8][64][8]     = 12,582,912
#define OFF_VF    13590528                 // bf16 [B_][6][2][4][64][8]  = 12,582,912
// total 26,173,440 B

// One kernel for all precomputation: biasF (98304 thr) + wkvF/wqF/wpF (110592 thr)
__global__ __launch_bounds__(256)
void precomp_all(const float* __restrict__ w_kv, const float* __restrict__ w_q,
                 const float* __restrict__ w_proj, const float* __restrict__ bias_table,
                 const int* __restrict__ rel_index,
                 bf16* __restrict__ biasF, bf16* __restrict__ wkvF,
                 bf16* __restrict__ wqF, bf16* __restrict__ wpF)
{
    const int i = blockIdx.x * 256 + threadIdx.x;   // 208896 total
    if (i < 98304) {                                // biasF[h][rowblk][tl][lane][r]  (bf16)
        const int lane = i & 63, tl = (i >> 6) & 7, rowblk = (i >> 9) & 31, h = i >> 14;
        const int quad = lane >> 4, l16 = lane & 15;
        const int kvi = tl * 16 + l16;
        __align__(8) bf16 vr[4];
        #pragma unroll
        for (int r = 0; r < 4; ++r) {
            const int qrow = rowblk * 16 + quad * 4 + r;
            vr[r] = __float2bfloat16(bias_table[rel_index[qrow * NKV + kvi] * NH + h] * LOG2E);
        }
        *(uint2*)&biasF[i * 4] = *(uint2*)vr;
    } else if (i < 98304 + 73728) {                 // wkvF[nt24][kk6][lane][j]
        const int i1 = i - 98304;
        const int j = i1 & 7, lane = (i1 >> 3) & 63, kk = (i1 >> 9) % 6, nt = i1 / 3072;
        const int quad = lane >> 4, l16 = lane & 15;
        wkvF[i1] = __float2bfloat16(w_kv[(kk * 32 + quad * 8 + j) * (2 * CDIM) + nt * 16 + l16]);
    } else if (i < 98304 + 92160) {                 // wqF[h][tl2][kk3][lane][j]
        const int i2 = i - 98304 - 73728;
        const int j = i2 & 7, lane = (i2 >> 3) & 63, kk = (i2 >> 9) % 3,
                  tl = (i2 / 1536) & 1, h = i2 / 3072;
        const int quad = lane >> 4, l16 = lane & 15;
        wqF[i2] = __float2bfloat16(w_q[(kk * 32 + quad * 8 + j) * CDIM + h * DH + tl * 16 + l16]
                                   * (SCALE * LOG2E));
    } else {                                        // wpF[h][tn6][lane][j]
        const int i3 = i - 98304 - 92160;
        const int j = i3 & 7, lane = (i3 >> 3) & 63, tn = (i3 >> 9) % 6, h = i3 / 3072;
        const int quad = lane >> 4, l16 = lane & 15;
        wpF[i3] = __float2bfloat16(w_proj[(h * DH + quad * 8 + j) * QCDIM + tn * 16 + l16]);
    }
}

// Per (batch, half): half 0 -> K' -> KF frag order; half 1 -> V' -> VF frag order.
__global__ __launch_bounds__(512, 4)
void proj_kv(const float* __restrict__ kv, const float* __restrict__ b_kv,
             const bf16* __restrict__ wkvF, bf16* __restrict__ KF, bf16* __restrict__ VF)
{
    __shared__ __align__(16) char smem[52224];
    bf16* sA = (bf16*)smem;                        // staging [128][200]
    const int b = blockIdx.x, half = blockIdx.y, t = threadIdx.x;
    const int w = t >> 6, lane = t & 63, quad = lane >> 4, l16 = lane & 15;
    const f32x4 ZV = {0.f, 0.f, 0.f, 0.f};

    for (int f = t; f < 6144; f += 512) {
        const int r = f / 48, c4 = f % 48;
        const float4 v = *(const float4*)&kv[((size_t)b * NKV + r) * CDIM + c4 * 4];
        __align__(8) bf16 tmp[4] = {__float2bfloat16(v.x), __float2bfloat16(v.y),
                                    __float2bfloat16(v.z), __float2bfloat16(v.w)};
        *(uint2*)&sA[r * 200 + c4 * 4] = *(uint2*)tmp;
    }
    __syncthreads();

    f32x4 acc[12];
    #pragma unroll
    for (int i = 0; i < 12; ++i) acc[i] = ZV;
    for (int kk = 0; kk < 6; ++kk) {
        const s16x8 a = *(const s16x8*)&sA[(w * 16 + l16) * 200 + kk * 32 + quad * 8];
        #pragma unroll
        for (int nt = 0; nt < 12; ++nt) {
            const s16x8 bb = *(const s16x8*)&wkvF[(((half * 12 + nt) * 6 + kk) * 64 + lane) * 8];
            acc[nt] = MFMA16(a, bb, acc[nt]);
        }
    }
    __syncthreads();   // staging dead; reuse smem as transpose buffer

    if (half == 0) {
        bf16* bufK = (bf16*)smem;                  // K' [128][200]
        #pragma unroll
        for (int nt = 0; nt < 12; ++nt) {
            const int col = nt * 16 + l16;
            const float bias = b_kv[col];
            #pragma unroll
            for (int r = 0; r < 4; ++r)
                bufK[(w * 16 + quad * 4 + r) * 200 + col] = __float2bfloat16(acc[nt][r] + bias);
        }
        __syncthreads();
        bf16* KF_b = KF + (size_t)b * 24576;       // [h][tl8][lane][8]
        #pragma unroll
        for (int i = 0; i < 6; ++i) {
            const int fr = w * 6 + i, h = fr >> 3, tl = fr & 7;
            const s16x8 v = *(const s16x8*)&bufK[(tl * 16 + l16) * 200 + h * DH + quad * 8];
            *(s16x8*)&KF_b[(size_t)(fr * 64 + lane) * 8] = v;
        }
    } else {
        bf16* bufV = (bf16*)smem;                  // V'^T [192][136]
        #pragma unroll
        for (int nt = 0; nt < 12; ++nt) {
            const int d = nt * 16 + l16;
            const float bias = b_kv[CDIM + d];
            __align__(8) bf16 tmp[4];
            #pragma unroll
            for (int r = 0; r < 4; ++r) tmp[r] = __float2bfloat16(acc[nt][r] + bias);
            *(uint2*)&bufV[d * 136 + w * 16 + quad * 4] = *(uint2*)tmp;
        }
        __syncthreads();
        bf16* VF_b = VF + (size_t)b * 24576;       // [h][tl2][kk4][lane][8]
        #pragma unroll
        for (int i = 0; i < 6; ++i) {
            const int fr = w * 6 + i, h = fr >> 3, tl = (fr >> 2) & 1, kk = fr & 3;
            const s16x8 v = *(const s16x8*)&bufV[(h * DH + tl * 16 + l16) * 136 + kk * 32 + quad * 8];
            *(s16x8*)&VF_b[(size_t)(fr * 64 + lane) * 8] = v;
        }
    }
}

// Per (batch, 16-row chain): grid (B, 8), 4 waves, each wave ONE chain.
// PREFETCH-STRUCTURED: all of head h's B-side fragments are issued in source
// order ahead of their consuming phase (KF/bias/wq up front; VF during the Q'
// LDS bounce; wp during the P bounce) so L2 latency hides under compute.
// launch_bounds(256,4): 128-reg budget for the prefetch window; LDS 17.4 KB.
// b fastest in dispatch keeps b->XCD fixed across y-generations (L2 reuse).
__global__ __launch_bounds__(256, 4)
void attn_fused(const float* __restrict__ q, const float* __restrict__ b_q,
                const float* __restrict__ b_proj, const char* __restrict__ wsro,
                float* __restrict__ out)
{
    __shared__ __align__(16) bf16 sP[4 * 16 * 136];   // 17,408 B
    const int b = blockIdx.x, y = blockIdx.y;         // y in 0..7
    const int t = threadIdx.x;
    const int w = t >> 6, lane = t & 63, quad = lane >> 4, l16 = lane & 15;

    const bf16* biasF = (const bf16*)(wsro + OFF_BIASF);
    const bf16* wqF   = (const bf16*)(wsro + OFF_WQF);
    const bf16* wpF   = (const bf16*)(wsro + OFF_WPF);
    const bf16* KF_b  = (const bf16*)(wsro + OFF_KF) + (size_t)b * 24576;
    const bf16* VF_b  = (const bf16*)(wsro + OFF_VF) + (size_t)b * 24576;

    const int rb = y * 4 + w;                         // row-block 0..31
    bf16* myP = sP + w * 2176;

    // q A-fragments, fp32 -> bf16 in-kernel
    s16x8 qa[3];
    #pragma unroll
    for (int kk = 0; kk < 3; ++kk) {
        const float* src = &q[((size_t)b * NQ + rb * 16 + l16) * QCDIM + kk * 32 + quad * 8];
        const float4 a0 = *(const float4*)src;
        const float4 a1 = *(const float4*)(src + 4);
        __align__(16) bf16 tmp[8] = {
            __float2bfloat16(a0.x), __float2bfloat16(a0.y), __float2bfloat16(a0.z),
            __float2bfloat16(a0.w), __float2bfloat16(a1.x), __float2bfloat16(a1.y),
            __float2bfloat16(a1.z), __float2bfloat16(a1.w)};
        qa[kk] = *(s16x8*)tmp;
    }

    // out accumulator initialized with b_proj (folds the epilogue bias add)
    f32x4 outacc[6];
    #pragma unroll
    for (int tn = 0; tn < 6; ++tn) {
        const float bp = b_proj[tn * 16 + l16];
        outacc[tn] = (f32x4){bp, bp, bp, bp};
    }

    for (int h = 0; h < NH; ++h) {
        // ---- issue S-phase loads FIRST: KF(8) + bias(8, bf16) + wq(6) ----
        s16x8 kf[8];
        #pragma unroll
        for (int t4 = 0; t4 < 8; ++t4)
            kf[t4] = *(const s16x8*)&KF_b[(size_t)((h * 8 + t4) * 64 + lane) * 8];
        s16x4 bb[8];
        #pragma unroll
        for (int t4 = 0; t4 < 8; ++t4)
            bb[t4] = *(const s16x4*)&biasF[(((h * 32 + rb) * 8 + t4) * 64 + lane) * 4];
        s16x8 wqf[6];
        #pragma unroll
        for (int i = 0; i < 6; ++i)
            wqf[i] = *(const s16x8*)&wqF[((h * 6 + i) * 64 + lane) * 8];

        // ---- (a) Q'_h = q @ wq_h (pre-scaled SCALE*LOG2E) + b_q splat ----
        f32x4 qacc[2];
        #pragma unroll
        for (int tl = 0; tl < 2; ++tl) {
            const float bq = b_q[h * DH + tl * 16 + l16] * (SCALE * LOG2E);
            qacc[tl] = (f32x4){bq, bq, bq, bq};
        }
        #pragma unroll
        for (int kk = 0; kk < 3; ++kk)
            #pragma unroll
            for (int tl = 0; tl < 2; ++tl)
                qacc[tl] = MFMA16(qa[kk], wqf[tl * 3 + kk], qacc[tl]);
        #pragma unroll
        for (int tl = 0; tl < 2; ++tl)
            #pragma unroll
            for (int r = 0; r < 4; ++r)
                myP[(quad * 4 + r) * 136 + tl * 16 + l16] = __float2bfloat16(qacc[tl][r]);

        // ---- issue V fragments now (consumed after the exp phase) ----
        s16x8 vf[8];
        #pragma unroll
        for (int i = 0; i < 8; ++i)
            vf[i] = *(const s16x8*)&VF_b[(size_t)((h * 8 + i) * 64 + lane) * 8];

        const s16x8 aQ = *(const s16x8*)&myP[l16 * 136 + quad * 8];

        // ---- (b) S = Q'K'^T + bias (bf16 C-init); 2^S; P; row-sums ----
        f32x4 sacc[8];
        #pragma unroll
        for (int t4 = 0; t4 < 8; ++t4)
            #pragma unroll
            for (int r = 0; r < 4; ++r)
                sacc[t4][r] = b2f(bb[t4][r]);
        #pragma unroll
        for (int t4 = 0; t4 < 8; ++t4)
            sacc[t4] = MFMA16(aQ, kf[t4], sacc[t4]);
        float rs[4] = {0.f, 0.f, 0.f, 0.f};
        #pragma unroll
        for (int t4 = 0; t4 < 8; ++t4)
            #pragma unroll
            for (int r = 0; r < 4; ++r) {
                const float vv = __builtin_amdgcn_exp2f(sacc[t4][r]);
                rs[r] += vv;
                myP[(quad * 4 + r) * 136 + t4 * 16 + l16] = __float2bfloat16(vv);
            }

        // ---- issue out-proj fragments (consumed after PV) ----
        s16x8 wpf[6];
        #pragma unroll
        for (int i = 0; i < 6; ++i)
            wpf[i] = *(const s16x8*)&wpF[((h * 6 + i) * 64 + lane) * 8];

        float inv[4];
        #pragma unroll
        for (int r = 0; r < 4; ++r) {
            float s = rs[r];
            #pragma unroll
            for (int off = 1; off < 16; off <<= 1) s += __shfl_xor(s, off, 16);
            inv[r] = 1.f / s;
        }

        // ---- (c) O_h = P_unnorm @ V'_h, scaled by inv ----
        f32x4 oacc[2];
        oacc[0] = (f32x4){0.f, 0.f, 0.f, 0.f};
        oacc[1] = (f32x4){0.f, 0.f, 0.f, 0.f};
        #pragma unroll
        for (int kk = 0; kk < 4; ++kk) {
            const s16x8 aP = *(const s16x8*)&myP[l16 * 136 + kk * 32 + quad * 8];
            #pragma unroll
            for (int tl = 0; tl < 2; ++tl)
                oacc[tl] = MFMA16(aP, vf[tl * 4 + kk], oacc[tl]);
        }
        #pragma unroll
        for (int tl = 0; tl < 2; ++tl)
            #pragma unroll
            for (int r = 0; r < 4; ++r)
                myP[(quad * 4 + r) * 136 + tl * 16 + l16] = __float2bfloat16(oacc[tl][r] * inv[r]);

        // ---- (d) out += O_h @ wp_h ----
        const s16x8 aO = *(const s16x8*)&myP[l16 * 136 + quad * 8];
        #pragma unroll
        for (int tn = 0; tn < 6; ++tn)
            outacc[tn] = MFMA16(aO, wpf[tn], outacc[tn]);
    }

    #pragma unroll
    for (int tn = 0; tn < 6; ++tn)
        #pragma unroll
        for (int r = 0; r < 4; ++r)
            out[((size_t)b * NQ + rb * 16 + quad * 4 + r) * QCDIM + tn * 16 + l16]
                = outacc[tn][r];
}

extern "C" void kernel_launch(void* const* d_in, const int* in_sizes, int n_in,
                              void* d_out, int out_size, void* d_ws, size_t ws_size,
                              hipStream_t stream)
{
    const float* kv       = (const float*)d_in[0];
    const float* q        = (const float*)d_in[1];
    const float* w_kv     = (const float*)d_in[2];
    const float* b_kv     = (const float*)d_in[3];
    const float* w_q      = (const float*)d_in[4];
    const float* b_q      = (const float*)d_in[5];
    const float* w_proj   = (const float*)d_in[6];
    const float* b_proj   = (const float*)d_in[7];
    const float* bias_tab = (const float*)d_in[8];
    const int*   rel_idx  = (const int*)d_in[9];
    char* ws = (char*)d_ws;

    precomp_all<<<816, 256, 0, stream>>>(w_kv, w_q, w_proj, bias_tab, rel_idx,
                                         (bf16*)(ws + OFF_BIASF), (bf16*)(ws + OFF_WKVF),
                                         (bf16*)(ws + OFF_WQF), (bf16*)(ws + OFF_WPF));
    proj_kv<<<dim3(B_, 2), 512, 0, stream>>>(kv, b_kv, (const bf16*)(ws + OFF_WKVF),
                                             (bf16*)(ws + OFF_KF), (bf16*)(ws + OFF_VF));
    attn_fused<<<dim3(B_, 8), 256, 0, stream>>>(q, b_q, b_proj, (const char*)ws,
                                                (float*)d_out);
}